// Round 3
// baseline (2424.296 us; speedup 1.0000x reference)
//
#include <hip/hip_runtime.h>
#include <hip/hip_bf16.h>
#include <cstdint>
#include <cstddef>

// SlotAttentionV2 forward, MI355X.
// K1 (MFMA, operand-swapped): LN + K/V projection -> bf16 workspace.
//   D = W · xhat^T so each thread holds 4 consecutive output dims -> 8B stores.
// K2: one 1024-thread block per batch (16 waves, LDS-bound 1 block/CU),
//   __launch_bounds__(1024,4) -> 128 VGPR budget (R2's 64-VGPR spill fix).

#define B_   256
#define N_   4096
#define NS_  8
#define D_   64
#define EPS_   1e-8f
#define SCALE_ 0.125f
#define OUT_SLOTS_ (B_ * NS_ * D_)   // 131072
#define NTILES_ (B_ * N_ / 64)       // 16384

typedef unsigned short u16;
typedef unsigned int   u32;
typedef short s16x8 __attribute__((ext_vector_type(8)));
typedef float f32x4 __attribute__((ext_vector_type(4)));

__device__ inline float bf2f(u16 u) {
  union { u32 i; float f; } c; c.i = ((u32)u) << 16; return c.f;
}
__device__ inline u16 f2bf(float f) {
  union { u32 i; float f; } c; c.f = f;
  return (u16)((c.i + 0x7fffu + ((c.i >> 16) & 1u)) >> 16);
}
__device__ inline void bf2x2(u32 u, float& lo, float& hi) {
  union { u32 i; float f; } a, b;
  a.i = u << 16; b.i = u & 0xffff0000u;
  lo = a.f; hi = b.f;
}
__device__ inline float wredsum(float v) {
  #pragma unroll
  for (int o = 32; o; o >>= 1) v += __shfl_xor(v, o, 64);
  return v;
}

// ---------------- Kernel 1: LN(inputs) -> K, V (bf16) via MFMA ----------------
// Block: 256 thr (4 waves), 64-row tile per step, grid-stride, prefetched.
// A-frag = W rows (m = output dim), B-frag = xhat (n = pixel row).
// Thread (col, kg) holds D[kg*4+r][col] = out[pixel w*16+col][dim mt*16+kg*4+r].
__global__ __launch_bounds__(256, 3) void k_lnkv(
    const float* __restrict__ x,
    const float* __restrict__ ni_g, const float* __restrict__ ni_b,
    const float* __restrict__ Wk, const float* __restrict__ bk,
    const float* __restrict__ Wv, const float* __restrict__ bv,
    u16* __restrict__ K, u16* __restrict__ V)
{
  __shared__ u16 xsh[64 * 72];
  __shared__ float gsh[64], bsh[64];
  const int tid  = threadIdx.x;
  const int lane = tid & 63;
  const int w    = tid >> 6;      // wave 0..3 -> pixel group (n-tile)
  const int col  = lane & 15;     // MFMA col: pixel within group
  const int kg   = lane >> 4;     // quad 0..3

  if (tid < 64) { gsh[tid] = ni_g[tid]; bsh[tid] = ni_b[tid]; }

  // A-frags (W): af[kstep][t]; t 0-3 -> K dim-tiles, 4-7 -> V dim-tiles.
  // A[m=lane&15][k=kg*8+j]: lane reads W[mt*16+col][ks*32+kg*8 ..+7].
  s16x8 af[2][8];
  f32x4 bias4[8];
  #pragma unroll
  for (int t = 0; t < 8; t++) {
    const float* W = (t < 4) ? Wk : Wv;
    const float* bb = (t < 4) ? bk : bv;
    const int m = (t & 3) * 16 + col;
    float4 b4 = *(const float4*)(bb + (t & 3) * 16 + kg * 4);
    bias4[t][0] = b4.x; bias4[t][1] = b4.y; bias4[t][2] = b4.z; bias4[t][3] = b4.w;
    #pragma unroll
    for (int ks = 0; ks < 2; ks++) {
      const float* src = W + m * 64 + ks * 32 + kg * 8;
      float4 w0 = *(const float4*)(src);
      float4 w1 = *(const float4*)(src + 4);
      union { s16x8 v; u16 u[8]; } pk;
      pk.u[0] = f2bf(w0.x); pk.u[1] = f2bf(w0.y);
      pk.u[2] = f2bf(w0.z); pk.u[3] = f2bf(w0.w);
      pk.u[4] = f2bf(w1.x); pk.u[5] = f2bf(w1.y);
      pk.u[6] = f2bf(w1.z); pk.u[7] = f2bf(w1.w);
      af[ks][t] = pk.v;
    }
  }

  // LN lane mapping: thread = (row xr, quarter xc), 16 contiguous cols.
  const int xr = tid >> 2;
  const int xc = tid & 3;

  int tile = blockIdx.x;
  float4 xv[4];
  {
    const float* Xrow = x + ((size_t)tile * 64 + xr) * 64 + xc * 16;
    #pragma unroll
    for (int j = 0; j < 4; j++) xv[j] = *(const float4*)(Xrow + j * 4);
  }
  __syncthreads();  // gsh/bsh ready

  while (tile < NTILES_) {
    // ---- LN + pack to LDS
    float s = 0.f;
    #pragma unroll
    for (int j = 0; j < 4; j++) s += xv[j].x + xv[j].y + xv[j].z + xv[j].w;
    s += __shfl_xor(s, 1, 64); s += __shfl_xor(s, 2, 64);
    const float m = s * (1.0f / 64.0f);
    float vs = 0.f;
    #pragma unroll
    for (int j = 0; j < 4; j++) {
      float a0 = xv[j].x - m, a1 = xv[j].y - m, a2 = xv[j].z - m, a3 = xv[j].w - m;
      vs += a0*a0 + a1*a1 + a2*a2 + a3*a3;
    }
    vs += __shfl_xor(vs, 1, 64); vs += __shfl_xor(vs, 2, 64);
    const float rs = rsqrtf(vs * (1.0f / 64.0f) + 1e-5f);
    u32 pk[8];
    #pragma unroll
    for (int j = 0; j < 4; j++) {
      float4 g4 = *(const float4*)(gsh + xc * 16 + j * 4);
      float4 b4 = *(const float4*)(bsh + xc * 16 + j * 4);
      float h0 = (xv[j].x - m) * rs * g4.x + b4.x;
      float h1 = (xv[j].y - m) * rs * g4.y + b4.y;
      float h2 = (xv[j].z - m) * rs * g4.z + b4.z;
      float h3 = (xv[j].w - m) * rs * g4.w + b4.w;
      pk[j*2+0] = (u32)f2bf(h0) | ((u32)f2bf(h1) << 16);
      pk[j*2+1] = (u32)f2bf(h2) | ((u32)f2bf(h3) << 16);
    }
    u32* dst = (u32*)(xsh + xr * 72 + xc * 16);
    ((uint4*)dst)[0] = make_uint4(pk[0], pk[1], pk[2], pk[3]);
    ((uint4*)dst)[1] = make_uint4(pk[4], pk[5], pk[6], pk[7]);
    __syncthreads();

    // ---- prefetch next tile (overlaps MFMA + stores)
    const int nxt = tile + (int)gridDim.x;
    float4 xn[4];
    if (nxt < NTILES_) {
      const float* Xrow = x + ((size_t)nxt * 64 + xr) * 64 + xc * 16;
      #pragma unroll
      for (int j = 0; j < 4; j++) xn[j] = *(const float4*)(Xrow + j * 4);
    }

    // ---- MFMA: B-frag = xhat rows of this wave's 16 pixels
    const u16* ar = xsh + (w * 16 + col) * 72 + kg * 8;
    union { uint4 q; s16x8 v; } ub0, ub1;
    ub0.q = *(const uint4*)(ar);
    ub1.q = *(const uint4*)(ar + 32);
    const size_t xrow = (size_t)tile * 64 + w * 16 + col;
    #pragma unroll
    for (int t = 0; t < 8; t++) {
      f32x4 a = bias4[t];
      a = __builtin_amdgcn_mfma_f32_16x16x32_bf16(af[0][t], ub0.v, a, 0, 0, 0);
      a = __builtin_amdgcn_mfma_f32_16x16x32_bf16(af[1][t], ub1.v, a, 0, 0, 0);
      u16* outp = ((t < 4) ? K : V) + xrow * 64 + (t & 3) * 16 + kg * 4;
      uint2 st;
      st.x = (u32)f2bf(a[0]) | ((u32)f2bf(a[1]) << 16);
      st.y = (u32)f2bf(a[2]) | ((u32)f2bf(a[3]) << 16);
      *(uint2*)outp = st;
    }
    __syncthreads();
    #pragma unroll
    for (int j = 0; j < 4; j++) xv[j] = xn[j];
    tile = nxt;
  }
}

// ---------------- Kernel 2: block-per-batch slot attention (1024 thr) --------
// LDS (dynamic, 86080 B): attn u16[8][4096] | q f32[8][64] | sl | sp | upd |
// prior f32[8][128] | hid | post | Ssum[8] | kl[8]
__global__ __launch_bounds__(1024, 4) void k_slot(
    const u16* __restrict__ K, const u16* __restrict__ V,
    const float* __restrict__ slots0, const float* __restrict__ prior_slots,
    const float* __restrict__ eps_noise,
    const float* __restrict__ npf_g, const float* __restrict__ npf_b,
    const float* __restrict__ Wq, const float* __restrict__ bq,
    const float* __restrict__ sr_W1, const float* __restrict__ sr_b1,
    const float* __restrict__ sr_W2, const float* __restrict__ sr_b2,
    const float* __restrict__ pr_W1, const float* __restrict__ pr_b1,
    const float* __restrict__ pr_W2, const float* __restrict__ pr_b2,
    const float* __restrict__ gWih, const float* __restrict__ gWhh,
    const float* __restrict__ gbih, const float* __restrict__ gbhh,
    const float* __restrict__ mW1, const float* __restrict__ mb1,
    const float* __restrict__ mW2, const float* __restrict__ mb2,
    float* __restrict__ out)
{
  extern __shared__ char smem[];
  u16*   attn_u  = (u16*)smem;                  // 65536
  float* q_f     = (float*)(smem + 65536);      // 2048
  float* sl_f    = (float*)(smem + 67584);      // 2048
  float* sp_f    = (float*)(smem + 69632);      // 2048
  float* upd_f   = (float*)(smem + 71680);      // 2048
  float* prior_f = (float*)(smem + 73728);      // 4096
  float* hid_f   = (float*)(smem + 77824);      // 4096
  float* post_f  = (float*)(smem + 81920);      // 4096
  float* Ssum    = (float*)(smem + 86016);      // 32
  float* kl_f    = (float*)(smem + 86048);      // 32

  const int tid  = threadIdx.x;    // 0..1023
  const int wv   = tid >> 6;       // wave 0..15
  const int lane = tid & 63;
  const int b    = blockIdx.x;
  const u16* Kb = K + (size_t)b * (N_ * 64);
  const u16* Vb = V + (size_t)b * (N_ * 64);

  // ---- P0.1: slots load + prior hidden
  if (tid < 512) sl_f[tid] = slots0[(size_t)b * 512 + tid];
  {
    int s = tid >> 7, h = tid & 127;
    const float* xr = prior_slots + ((size_t)b * 8 + s) * 64;
    const float* wr = pr_W1 + h * 64;
    float a = pr_b1[h];
    #pragma unroll
    for (int ec = 0; ec < 16; ec++) {
      float4 xe = ((const float4*)xr)[ec];
      float4 w  = ((const float4*)wr)[ec];
      a = fmaf(xe.x, w.x, a); a = fmaf(xe.y, w.y, a);
      a = fmaf(xe.z, w.z, a); a = fmaf(xe.w, w.w, a);
    }
    hid_f[tid] = fmaxf(a, 0.f);
  }
  __syncthreads();
  // ---- P0.2: prior
  {
    int s = tid >> 7, o = tid & 127;
    const float* hh = hid_f + s * 128;
    const float* wr = pr_W2 + o * 128;
    float a = pr_b2[o];
    #pragma unroll
    for (int ec = 0; ec < 32; ec++) {
      float4 xe = ((const float4*)hh)[ec];
      float4 w  = ((const float4*)wr)[ec];
      a = fmaf(xe.x, w.x, a); a = fmaf(xe.y, w.y, a);
      a = fmaf(xe.z, w.z, a); a = fmaf(xe.w, w.w, a);
    }
    prior_f[tid] = a;
  }
  __syncthreads();
  // ---- P0.3: sms hidden
  {
    int s = tid >> 7, h = tid & 127;
    const float* xr = sl_f + s * 64;
    const float* wr = sr_W1 + h * 64;
    float a = sr_b1[h];
    #pragma unroll
    for (int ec = 0; ec < 16; ec++) {
      float4 xe = ((const float4*)xr)[ec];
      float4 w  = ((const float4*)wr)[ec];
      a = fmaf(xe.x, w.x, a); a = fmaf(xe.y, w.y, a);
      a = fmaf(xe.z, w.z, a); a = fmaf(xe.w, w.w, a);
    }
    hid_f[tid] = fmaxf(a, 0.f);
  }
  __syncthreads();
  // ---- P0.4: sms -> post
  {
    int s = tid >> 7, o = tid & 127;
    const float* hh = hid_f + s * 128;
    const float* wr = sr_W2 + o * 128;
    float a = sr_b2[o];
    #pragma unroll
    for (int ec = 0; ec < 32; ec++) {
      float4 xe = ((const float4*)hh)[ec];
      float4 w  = ((const float4*)wr)[ec];
      a = fmaf(xe.x, w.x, a); a = fmaf(xe.y, w.y, a);
      a = fmaf(xe.z, w.z, a); a = fmaf(xe.w, w.w, a);
    }
    post_f[tid] = a;
  }
  __syncthreads();
  // ---- P0.5: reparam
  if (tid < 512) {
    int s = tid >> 6, d = tid & 63;
    float mu = post_f[s * 128 + d];
    float lv = post_f[s * 128 + 64 + d];
    sl_f[tid] = eps_noise[(size_t)b * 512 + tid] * __expf(0.5f * lv) + mu;
  }
  if (tid < 8) kl_f[tid] = 0.f;
  __syncthreads();

  // ---- iterations ----
  #pragma unroll 1
  for (int it = 0; it < 3; it++) {
    // I1: snapshot, zero, q = slots @ Wq.T + bq
    if (tid < 512) {
      sp_f[tid]  = sl_f[tid];
      upd_f[tid] = 0.f;
      int s = tid >> 6, d = tid & 63;
      const float* xr = sl_f + s * 64;
      const float* wr = Wq + d * 64;
      float a = bq[d];
      #pragma unroll
      for (int ec = 0; ec < 16; ec++) {
        float4 xe = ((const float4*)xr)[ec];
        float4 w  = ((const float4*)wr)[ec];
        a = fmaf(xe.x, w.x, a); a = fmaf(xe.y, w.y, a);
        a = fmaf(xe.z, w.z, a); a = fmaf(xe.w, w.w, a);
      }
      q_f[tid] = a;
    }
    if (tid < 8) Ssum[tid] = 0.f;
    __syncthreads();

    // I2: pass A — 4 px/thread (2 steps x 2 px)
    float s_loc[8];
    #pragma unroll
    for (int i = 0; i < 8; i++) s_loc[i] = 0.f;
    #pragma unroll 1
    for (int st = 0; st < 2; st++) {
      const int j1 = st * 2048 + tid;
      const int j2 = j1 + 1024;
      uint4 kr1[8], kr2[8];
      const uint4* p1 = (const uint4*)(Kb + (size_t)j1 * 64);
      const uint4* p2 = (const uint4*)(Kb + (size_t)j2 * 64);
      #pragma unroll
      for (int c = 0; c < 8; c++) { kr1[c] = p1[c]; kr2[c] = p2[c]; }
      float d1[8], d2[8];
      #pragma unroll
      for (int i = 0; i < 8; i++) {
        const float4* qr = (const float4*)(q_f + i * 64);
        float a1 = 0.f, a2 = 0.f;
        #pragma unroll
        for (int c = 0; c < 8; c++) {
          float4 qa = qr[c * 2], qb = qr[c * 2 + 1];
          float x0,x1,x2,x3,x4,x5,x6,x7;
          bf2x2(kr1[c].x, x0, x1); bf2x2(kr1[c].y, x2, x3);
          bf2x2(kr1[c].z, x4, x5); bf2x2(kr1[c].w, x6, x7);
          a1 = fmaf(qa.x,x0,a1); a1 = fmaf(qa.y,x1,a1);
          a1 = fmaf(qa.z,x2,a1); a1 = fmaf(qa.w,x3,a1);
          a1 = fmaf(qb.x,x4,a1); a1 = fmaf(qb.y,x5,a1);
          a1 = fmaf(qb.z,x6,a1); a1 = fmaf(qb.w,x7,a1);
          bf2x2(kr2[c].x, x0, x1); bf2x2(kr2[c].y, x2, x3);
          bf2x2(kr2[c].z, x4, x5); bf2x2(kr2[c].w, x6, x7);
          a2 = fmaf(qa.x,x0,a2); a2 = fmaf(qa.y,x1,a2);
          a2 = fmaf(qa.z,x2,a2); a2 = fmaf(qa.w,x3,a2);
          a2 = fmaf(qb.x,x4,a2); a2 = fmaf(qb.y,x5,a2);
          a2 = fmaf(qb.z,x6,a2); a2 = fmaf(qb.w,x7,a2);
        }
        d1[i] = a1 * SCALE_; d2[i] = a2 * SCALE_;
      }
      float m1 = d1[0], m2 = d2[0];
      #pragma unroll
      for (int i = 1; i < 8; i++) { m1 = fmaxf(m1, d1[i]); m2 = fmaxf(m2, d2[i]); }
      float sm1 = 0.f, sm2 = 0.f;
      #pragma unroll
      for (int i = 0; i < 8; i++) {
        d1[i] = __expf(d1[i] - m1); sm1 += d1[i];
        d2[i] = __expf(d2[i] - m2); sm2 += d2[i];
      }
      const float r1 = 1.0f / sm1, r2 = 1.0f / sm2;
      #pragma unroll
      for (int i = 0; i < 8; i++) {
        float a1 = fmaf(d1[i], r1, EPS_);
        float a2 = fmaf(d2[i], r2, EPS_);
        s_loc[i] += a1 + a2;
        attn_u[i * 4096 + j1] = f2bf(a1);
        attn_u[i * 4096 + j2] = f2bf(a2);
      }
    }
    #pragma unroll
    for (int i = 0; i < 8; i++) {
      float v = wredsum(s_loc[i]);
      if (lane == 0) atomicAdd(&Ssum[i], v);
    }
    __syncthreads();

    // I3: pass B — lane owns (px-group of 8, 8-dim chunk); uint4 V loads.
    {
      const int px_off = lane >> 3;        // 0..7
      const int dc = (lane & 7) * 8;       // dim chunk base
      float u[8][8];
      #pragma unroll
      for (int i = 0; i < 8; i++)
        #pragma unroll
        for (int dd = 0; dd < 8; dd++) u[i][dd] = 0.f;
      const int jbase = wv * 256;
      #pragma unroll 2
      for (int st = 0; st < 32; st++) {
        const int j = jbase + st * 8 + px_off;
        uint4 v4 = *(const uint4*)(Vb + (size_t)j * 64 + dc);
        float vv[8];
        bf2x2(v4.x, vv[0], vv[1]); bf2x2(v4.y, vv[2], vv[3]);
        bf2x2(v4.z, vv[4], vv[5]); bf2x2(v4.w, vv[6], vv[7]);
        #pragma unroll
        for (int i = 0; i < 8; i++) {
          float a = bf2f(attn_u[i * 4096 + j]);
          #pragma unroll
          for (int dd = 0; dd < 8; dd++) u[i][dd] = fmaf(a, vv[dd], u[i][dd]);
        }
      }
      #pragma unroll
      for (int i = 0; i < 8; i++)
        #pragma unroll
        for (int dd = 0; dd < 8; dd++)
          atomicAdd(upd_f + i * 64 + dc + dd, u[i][dd]);
    }
    __syncthreads();

    // I4+I5: GRU (1/S folded) + LN of GRU output
    if (tid < 512) {
      int s = tid >> 6, d = tid & 63;
      const float* ur  = upd_f + s * 64;
      const float* hr  = sp_f + s * 64;
      const float* wi0 = gWih + d * 64;
      const float* wi1 = gWih + (64 + d) * 64;
      const float* wi2 = gWih + (128 + d) * 64;
      const float* wh0 = gWhh + d * 64;
      const float* wh1 = gWhh + (64 + d) * 64;
      const float* wh2 = gWhh + (128 + d) * 64;
      float air=0.f, aiz=0.f, ain=0.f, ahr=0.f, ahz=0.f, ahn=0.f;
      #pragma unroll
      for (int ec = 0; ec < 16; ec++) {
        float4 xe = ((const float4*)ur)[ec];
        float4 he = ((const float4*)hr)[ec];
        float4 w;
        w = ((const float4*)wi0)[ec];
        air = fmaf(xe.x,w.x,air); air = fmaf(xe.y,w.y,air);
        air = fmaf(xe.z,w.z,air); air = fmaf(xe.w,w.w,air);
        w = ((const float4*)wi1)[ec];
        aiz = fmaf(xe.x,w.x,aiz); aiz = fmaf(xe.y,w.y,aiz);
        aiz = fmaf(xe.z,w.z,aiz); aiz = fmaf(xe.w,w.w,aiz);
        w = ((const float4*)wi2)[ec];
        ain = fmaf(xe.x,w.x,ain); ain = fmaf(xe.y,w.y,ain);
        ain = fmaf(xe.z,w.z,ain); ain = fmaf(xe.w,w.w,ain);
        w = ((const float4*)wh0)[ec];
        ahr = fmaf(he.x,w.x,ahr); ahr = fmaf(he.y,w.y,ahr);
        ahr = fmaf(he.z,w.z,ahr); ahr = fmaf(he.w,w.w,ahr);
        w = ((const float4*)wh1)[ec];
        ahz = fmaf(he.x,w.x,ahz); ahz = fmaf(he.y,w.y,ahz);
        ahz = fmaf(he.z,w.z,ahz); ahz = fmaf(he.w,w.w,ahz);
        w = ((const float4*)wh2)[ec];
        ahn = fmaf(he.x,w.x,ahn); ahn = fmaf(he.y,w.y,ahn);
        ahn = fmaf(he.z,w.z,ahn); ahn = fmaf(he.w,w.w,ahn);
      }
      float sinv = 1.0f / Ssum[s];
      float rr = 1.0f / (1.0f + __expf(-(air * sinv + gbih[d]      + ahr + gbhh[d])));
      float zz = 1.0f / (1.0f + __expf(-(aiz * sinv + gbih[64 + d] + ahz + gbhh[64 + d])));
      float nn = tanhf(ain * sinv + gbih[128 + d] + rr * (ahn + gbhh[128 + d]));
      float hnew = (1.0f - zz) * nn + zz * sp_f[tid];
      sl_f[tid] = hnew;
      float mm = wredsum(hnew) * (1.0f / 64.0f);
      float cc = hnew - mm;
      float va = wredsum(cc * cc) * (1.0f / 64.0f);
      q_f[tid] = cc * rsqrtf(va + 1e-5f) * npf_g[d] + npf_b[d];  // reuse q
    }
    __syncthreads();

    // I6a: mlp hidden
    {
      int s = tid >> 7, h = tid & 127;
      const float* xr = q_f + s * 64;
      const float* wr = mW1 + h * 64;
      float a = mb1[h];
      #pragma unroll
      for (int ec = 0; ec < 16; ec++) {
        float4 xe = ((const float4*)xr)[ec];
        float4 w  = ((const float4*)wr)[ec];
        a = fmaf(xe.x, w.x, a); a = fmaf(xe.y, w.y, a);
        a = fmaf(xe.z, w.z, a); a = fmaf(xe.w, w.w, a);
      }
      hid_f[tid] = fmaxf(a, 0.f);
    }
    __syncthreads();
    // I6b: slots += mlp out
    if (tid < 512) {
      int s = tid >> 6, d = tid & 63;
      const float* hh = hid_f + s * 128;
      const float* wr = mW2 + d * 128;
      float a = mb2[d];
      #pragma unroll
      for (int ec = 0; ec < 32; ec++) {
        float4 xe = ((const float4*)hh)[ec];
        float4 w  = ((const float4*)wr)[ec];
        a = fmaf(xe.x, w.x, a); a = fmaf(xe.y, w.y, a);
        a = fmaf(xe.z, w.z, a); a = fmaf(xe.w, w.w, a);
      }
      sl_f[tid] = sl_f[tid] + a;
    }
    __syncthreads();
    // I7a: post hidden
    {
      int s = tid >> 7, h = tid & 127;
      const float* xr = sl_f + s * 64;
      const float* wr = sr_W1 + h * 64;
      float a = sr_b1[h];
      #pragma unroll
      for (int ec = 0; ec < 16; ec++) {
        float4 xe = ((const float4*)xr)[ec];
        float4 w  = ((const float4*)wr)[ec];
        a = fmaf(xe.x, w.x, a); a = fmaf(xe.y, w.y, a);
        a = fmaf(xe.z, w.z, a); a = fmaf(xe.w, w.w, a);
      }
      hid_f[tid] = fmaxf(a, 0.f);
    }
    __syncthreads();
    // I7b: post
    {
      int s = tid >> 7, o = tid & 127;
      const float* hh = hid_f + s * 128;
      const float* wr = sr_W2 + o * 128;
      float a = sr_b2[o];
      #pragma unroll
      for (int ec = 0; ec < 32; ec++) {
        float4 xe = ((const float4*)hh)[ec];
        float4 w  = ((const float4*)wr)[ec];
        a = fmaf(xe.x, w.x, a); a = fmaf(xe.y, w.y, a);
        a = fmaf(xe.z, w.z, a); a = fmaf(xe.w, w.w, a);
      }
      post_f[tid] = a;
    }
    __syncthreads();
    // I8: KL accumulate
    if (tid < 512) {
      int s = tid >> 6, d = tid & 63;
      float m_po = post_f[s * 128 + d],  lv_po = post_f[s * 128 + 64 + d];
      float m_pr = prior_f[s * 128 + d], lv_pr = prior_f[s * 128 + 64 + d];
      float dm = m_po - m_pr;
      float term = lv_pr - lv_po + (__expf(lv_po) + dm * dm) * __expf(-lv_pr) - 1.0f;
      float tsum = wredsum(term);
      if (lane == 0) kl_f[s] += 0.5f * tsum;
    }
    __syncthreads();
  }

  if (tid < 512) out[(size_t)b * 512 + tid] = sl_f[tid];
  if (tid < 8)   out[OUT_SLOTS_ + b * 8 + tid] = kl_f[tid];
}

extern "C" void kernel_launch(void* const* d_in, const int* in_sizes, int n_in,
                              void* d_out, int out_size, void* d_ws, size_t ws_size,
                              hipStream_t stream) {
  (void)in_sizes; (void)n_in; (void)out_size; (void)ws_size;
  const float* inputs      = (const float*)d_in[0];
  const float* slots0      = (const float*)d_in[1];
  const float* prior_slots = (const float*)d_in[2];
  const float* eps_noise   = (const float*)d_in[3];
  const float* ni_g  = (const float*)d_in[4];
  const float* ni_b  = (const float*)d_in[5];
  const float* npf_g = (const float*)d_in[6];
  const float* npf_b = (const float*)d_in[7];
  const float* Wq = (const float*)d_in[8];   const float* bq = (const float*)d_in[9];
  const float* Wk = (const float*)d_in[10];  const float* bk = (const float*)d_in[11];
  const float* Wv = (const float*)d_in[12];  const float* bv = (const float*)d_in[13];
  const float* sr_W1 = (const float*)d_in[14]; const float* sr_b1 = (const float*)d_in[15];
  const float* sr_W2 = (const float*)d_in[16]; const float* sr_b2 = (const float*)d_in[17];
  const float* pr_W1 = (const float*)d_in[18]; const float* pr_b1 = (const float*)d_in[19];
  const float* pr_W2 = (const float*)d_in[20]; const float* pr_b2 = (const float*)d_in[21];
  const float* gWih = (const float*)d_in[22]; const float* gWhh = (const float*)d_in[23];
  const float* gbih = (const float*)d_in[24]; const float* gbhh = (const float*)d_in[25];
  const float* mW1 = (const float*)d_in[26]; const float* mb1 = (const float*)d_in[27];
  const float* mW2 = (const float*)d_in[28]; const float* mb2 = (const float*)d_in[29];

  u16* K = (u16*)d_ws;
  u16* V = K + (size_t)B_ * N_ * D_;

  k_lnkv<<<dim3(2048), dim3(256), 0, stream>>>(inputs, ni_g, ni_b, Wk, bk, Wv, bv, K, V);

  const int SMEM = 86080;
  hipFuncSetAttribute((const void*)k_slot, hipFuncAttributeMaxDynamicSharedMemorySize, SMEM);
  k_slot<<<dim3(256), dim3(1024), SMEM, stream>>>(
      K, V, slots0, prior_slots, eps_noise, npf_g, npf_b, Wq, bq,
      sr_W1, sr_b1, sr_W2, sr_b2, pr_W1, pr_b1, pr_W2, pr_b2,
      gWih, gWhh, gbih, gbhh, mW1, mb1, mW2, mb2, (float*)d_out);
}

// Round 4
// 1357.067 us; speedup vs baseline: 1.7864x; 1.7864x over previous
//
#include <hip/hip_runtime.h>
#include <hip/hip_bf16.h>
#include <cstdint>
#include <cstddef>

// SlotAttentionV2 forward, MI355X.
// K1 (MFMA): LN + K/V projection -> bf16 workspace. Double-buffered LDS.
// K2: one 512-thread block per batch. Pass A = MFMA QK^T + in-fragment softmax
//     (512 threads -> compiler gives 128+ VGPRs; R2/R3's 64-VGPR scratch spill
//      of the 64-acc pass-B array was the whole 1.9 ms).

#define B_   256
#define N_   4096
#define NS_  8
#define D_   64
#define EPS_   1e-8f
#define SCALE_ 0.125f
#define OUT_SLOTS_ (B_ * NS_ * D_)   // 131072
#define NTILES_ (B_ * N_ / 64)       // 16384
#define AP_ 4104                      // attn row stride (u16), padded

typedef unsigned short u16;
typedef unsigned int   u32;
typedef short s16x8 __attribute__((ext_vector_type(8)));
typedef float f32x4 __attribute__((ext_vector_type(4)));

__device__ inline float bf2f(u16 u) {
  union { u32 i; float f; } c; c.i = ((u32)u) << 16; return c.f;
}
__device__ inline u16 f2bf(float f) {
  union { u32 i; float f; } c; c.f = f;
  return (u16)((c.i + 0x7fffu + ((c.i >> 16) & 1u)) >> 16);
}
__device__ inline void bf2x2(u32 u, float& lo, float& hi) {
  union { u32 i; float f; } a, b;
  a.i = u << 16; b.i = u & 0xffff0000u;
  lo = a.f; hi = b.f;
}
__device__ inline float wredsum(float v) {
  #pragma unroll
  for (int o = 32; o; o >>= 1) v += __shfl_xor(v, o, 64);
  return v;
}

// ---------------- Kernel 1: LN(inputs) -> K, V (bf16) via MFMA ----------------
__global__ __launch_bounds__(256, 3) void k_lnkv(
    const float* __restrict__ x,
    const float* __restrict__ ni_g, const float* __restrict__ ni_b,
    const float* __restrict__ Wk, const float* __restrict__ bk,
    const float* __restrict__ Wv, const float* __restrict__ bv,
    u16* __restrict__ K, u16* __restrict__ V)
{
  __shared__ u16 xsh[2][64 * 72];
  __shared__ float gsh[64], bsh[64];
  const int tid  = threadIdx.x;
  const int lane = tid & 63;
  const int w    = tid >> 6;      // wave 0..3 -> pixel group (n-tile)
  const int col  = lane & 15;     // MFMA col: pixel within group
  const int kg   = lane >> 4;     // quad 0..3

  if (tid < 64) { gsh[tid] = ni_g[tid]; bsh[tid] = ni_b[tid]; }

  // A-frags (W rows): af[kstep][t]; t 0-3 -> K dim-tiles, 4-7 -> V dim-tiles.
  s16x8 af[2][8];
  f32x4 bias4[8];
  #pragma unroll
  for (int t = 0; t < 8; t++) {
    const float* W = (t < 4) ? Wk : Wv;
    const float* bb = (t < 4) ? bk : bv;
    const int m = (t & 3) * 16 + col;
    float4 b4 = *(const float4*)(bb + (t & 3) * 16 + kg * 4);
    bias4[t][0] = b4.x; bias4[t][1] = b4.y; bias4[t][2] = b4.z; bias4[t][3] = b4.w;
    #pragma unroll
    for (int ks = 0; ks < 2; ks++) {
      const float* src = W + m * 64 + ks * 32 + kg * 8;
      float4 w0 = *(const float4*)(src);
      float4 w1 = *(const float4*)(src + 4);
      union { s16x8 v; u16 u[8]; } pk;
      pk.u[0] = f2bf(w0.x); pk.u[1] = f2bf(w0.y);
      pk.u[2] = f2bf(w0.z); pk.u[3] = f2bf(w0.w);
      pk.u[4] = f2bf(w1.x); pk.u[5] = f2bf(w1.y);
      pk.u[6] = f2bf(w1.z); pk.u[7] = f2bf(w1.w);
      af[ks][t] = pk.v;
    }
  }

  const int xr = tid >> 2;
  const int xc = tid & 3;

  int tile = blockIdx.x;
  int pbuf = 0;
  float4 xv[4];
  {
    const float* Xrow = x + ((size_t)tile * 64 + xr) * 64 + xc * 16;
    #pragma unroll
    for (int j = 0; j < 4; j++) xv[j] = *(const float4*)(Xrow + j * 4);
  }
  __syncthreads();  // gsh/bsh ready

  while (tile < NTILES_) {
    // ---- LN + pack to LDS buffer pbuf
    float s = 0.f;
    #pragma unroll
    for (int j = 0; j < 4; j++) s += xv[j].x + xv[j].y + xv[j].z + xv[j].w;
    s += __shfl_xor(s, 1, 64); s += __shfl_xor(s, 2, 64);
    const float m = s * (1.0f / 64.0f);
    float vs = 0.f;
    #pragma unroll
    for (int j = 0; j < 4; j++) {
      float a0 = xv[j].x - m, a1 = xv[j].y - m, a2 = xv[j].z - m, a3 = xv[j].w - m;
      vs += a0*a0 + a1*a1 + a2*a2 + a3*a3;
    }
    vs += __shfl_xor(vs, 1, 64); vs += __shfl_xor(vs, 2, 64);
    const float rs = rsqrtf(vs * (1.0f / 64.0f) + 1e-5f);
    u32 pk[8];
    #pragma unroll
    for (int j = 0; j < 4; j++) {
      float4 g4 = *(const float4*)(gsh + xc * 16 + j * 4);
      float4 b4 = *(const float4*)(bsh + xc * 16 + j * 4);
      float h0 = (xv[j].x - m) * rs * g4.x + b4.x;
      float h1 = (xv[j].y - m) * rs * g4.y + b4.y;
      float h2 = (xv[j].z - m) * rs * g4.z + b4.z;
      float h3 = (xv[j].w - m) * rs * g4.w + b4.w;
      pk[j*2+0] = (u32)f2bf(h0) | ((u32)f2bf(h1) << 16);
      pk[j*2+1] = (u32)f2bf(h2) | ((u32)f2bf(h3) << 16);
    }
    u32* dst = (u32*)(xsh[pbuf] + xr * 72 + xc * 16);
    ((uint4*)dst)[0] = make_uint4(pk[0], pk[1], pk[2], pk[3]);
    ((uint4*)dst)[1] = make_uint4(pk[4], pk[5], pk[6], pk[7]);
    __syncthreads();

    // ---- prefetch next tile (overlaps MFMA + stores)
    const int nxt = tile + (int)gridDim.x;
    float4 xn[4];
    if (nxt < NTILES_) {
      const float* Xrow = x + ((size_t)nxt * 64 + xr) * 64 + xc * 16;
      #pragma unroll
      for (int j = 0; j < 4; j++) xn[j] = *(const float4*)(Xrow + j * 4);
    }

    // ---- MFMA: B-frag = xhat rows of this wave's 16 pixels
    const u16* ar = xsh[pbuf] + (w * 16 + col) * 72 + kg * 8;
    union { uint4 q; s16x8 v; } ub0, ub1;
    ub0.q = *(const uint4*)(ar);
    ub1.q = *(const uint4*)(ar + 32);
    const size_t xrow = (size_t)tile * 64 + w * 16 + col;
    #pragma unroll
    for (int t = 0; t < 8; t++) {
      f32x4 a = bias4[t];
      a = __builtin_amdgcn_mfma_f32_16x16x32_bf16(af[0][t], ub0.v, a, 0, 0, 0);
      a = __builtin_amdgcn_mfma_f32_16x16x32_bf16(af[1][t], ub1.v, a, 0, 0, 0);
      u16* outp = ((t < 4) ? K : V) + xrow * 64 + (t & 3) * 16 + kg * 4;
      uint2 st;
      st.x = (u32)f2bf(a[0]) | ((u32)f2bf(a[1]) << 16);
      st.y = (u32)f2bf(a[2]) | ((u32)f2bf(a[3]) << 16);
      *(uint2*)outp = st;
    }
    // no second barrier: next write goes to the other buffer
    #pragma unroll
    for (int j = 0; j < 4; j++) xv[j] = xn[j];
    tile = nxt;
    pbuf ^= 1;
  }
}

// ---------------- Kernel 2: block-per-batch slot attention (512 thr) --------
// LDS (dynamic, 88512 B):
//   attn u16[8][4104]  65664 @0
//   qbf  u16[16][72]    2304 @65664   (A-operand for QK^T, rows 8-15 zero)
//   ln   f32[512]       2048 @67968
//   sl   f32[512]       2048 @70016
//   sp   f32[512]       2048 @72064
//   upd  f32[512]       2048 @74112
//   prior f32[8][128]   4096 @76160
//   hid   f32[8][128]   4096 @80256
//   post  f32[8][128]   4096 @84352
//   Ssum f32[8]           32 @88448 | kl f32[8] 32 @88480
__global__ __launch_bounds__(512, 2) void k_slot(
    const u16* __restrict__ K, const u16* __restrict__ V,
    const float* __restrict__ slots0, const float* __restrict__ prior_slots,
    const float* __restrict__ eps_noise,
    const float* __restrict__ npf_g, const float* __restrict__ npf_b,
    const float* __restrict__ Wq, const float* __restrict__ bq,
    const float* __restrict__ sr_W1, const float* __restrict__ sr_b1,
    const float* __restrict__ sr_W2, const float* __restrict__ sr_b2,
    const float* __restrict__ pr_W1, const float* __restrict__ pr_b1,
    const float* __restrict__ pr_W2, const float* __restrict__ pr_b2,
    const float* __restrict__ gWih, const float* __restrict__ gWhh,
    const float* __restrict__ gbih, const float* __restrict__ gbhh,
    const float* __restrict__ mW1, const float* __restrict__ mb1,
    const float* __restrict__ mW2, const float* __restrict__ mb2,
    float* __restrict__ out)
{
  extern __shared__ char smem[];
  u16*   attn_u  = (u16*)smem;                  // 65664
  u16*   qbf     = (u16*)(smem + 65664);        // 2304
  float* ln_f    = (float*)(smem + 67968);      // 2048
  float* sl_f    = (float*)(smem + 70016);      // 2048
  float* sp_f    = (float*)(smem + 72064);      // 2048
  float* upd_f   = (float*)(smem + 74112);      // 2048
  float* prior_f = (float*)(smem + 76160);      // 4096
  float* hid_f   = (float*)(smem + 80256);      // 4096
  float* post_f  = (float*)(smem + 84352);      // 4096
  float* Ssum    = (float*)(smem + 88448);      // 32
  float* kl_f    = (float*)(smem + 88480);      // 32

  const int tid  = threadIdx.x;    // 0..511
  const int wv   = tid >> 6;       // wave 0..7
  const int lane = tid & 63;
  const int col  = lane & 15;      // MFMA n-col
  const int kg   = lane >> 4;      // quad
  const int b    = blockIdx.x;
  const u16* Kb = K + (size_t)b * (N_ * 64);
  const u16* Vb = V + (size_t)b * (N_ * 64);

  // ---- P0.1: slots load + prior hidden = relu(prior_slots @ pr_W1.T + pr_b1)
  sl_f[tid] = slots0[(size_t)b * 512 + tid];
  #pragma unroll
  for (int kk = 0; kk < 2; kk++) {
    int idx = tid + kk * 512;
    int s = idx >> 7, h = idx & 127;
    const float* xr = prior_slots + ((size_t)b * 8 + s) * 64;
    const float* wr = pr_W1 + h * 64;
    float a = pr_b1[h];
    #pragma unroll
    for (int ec = 0; ec < 16; ec++) {
      float4 xe = ((const float4*)xr)[ec];
      float4 w  = ((const float4*)wr)[ec];
      a = fmaf(xe.x, w.x, a); a = fmaf(xe.y, w.y, a);
      a = fmaf(xe.z, w.z, a); a = fmaf(xe.w, w.w, a);
    }
    hid_f[idx] = fmaxf(a, 0.f);
  }
  __syncthreads();
  // ---- P0.2: prior = hid @ pr_W2.T + pr_b2
  #pragma unroll
  for (int kk = 0; kk < 2; kk++) {
    int idx = tid + kk * 512;
    int s = idx >> 7, o = idx & 127;
    const float* hh = hid_f + s * 128;
    const float* wr = pr_W2 + o * 128;
    float a = pr_b2[o];
    #pragma unroll
    for (int ec = 0; ec < 32; ec++) {
      float4 xe = ((const float4*)hh)[ec];
      float4 w  = ((const float4*)wr)[ec];
      a = fmaf(xe.x, w.x, a); a = fmaf(xe.y, w.y, a);
      a = fmaf(xe.z, w.z, a); a = fmaf(xe.w, w.w, a);
    }
    prior_f[idx] = a;
  }
  __syncthreads();
  // ---- P0.3: sms hidden = relu(slots @ sr_W1.T + sr_b1)
  #pragma unroll
  for (int kk = 0; kk < 2; kk++) {
    int idx = tid + kk * 512;
    int s = idx >> 7, h = idx & 127;
    const float* xr = sl_f + s * 64;
    const float* wr = sr_W1 + h * 64;
    float a = sr_b1[h];
    #pragma unroll
    for (int ec = 0; ec < 16; ec++) {
      float4 xe = ((const float4*)xr)[ec];
      float4 w  = ((const float4*)wr)[ec];
      a = fmaf(xe.x, w.x, a); a = fmaf(xe.y, w.y, a);
      a = fmaf(xe.z, w.z, a); a = fmaf(xe.w, w.w, a);
    }
    hid_f[idx] = fmaxf(a, 0.f);
  }
  __syncthreads();
  // ---- P0.4: sms = hid @ sr_W2.T + sr_b2 -> post
  #pragma unroll
  for (int kk = 0; kk < 2; kk++) {
    int idx = tid + kk * 512;
    int s = idx >> 7, o = idx & 127;
    const float* hh = hid_f + s * 128;
    const float* wr = sr_W2 + o * 128;
    float a = sr_b2[o];
    #pragma unroll
    for (int ec = 0; ec < 32; ec++) {
      float4 xe = ((const float4*)hh)[ec];
      float4 w  = ((const float4*)wr)[ec];
      a = fmaf(xe.x, w.x, a); a = fmaf(xe.y, w.y, a);
      a = fmaf(xe.z, w.z, a); a = fmaf(xe.w, w.w, a);
    }
    post_f[idx] = a;
  }
  __syncthreads();
  // ---- P0.5: reparam
  {
    int s = tid >> 6, d = tid & 63;
    float mu = post_f[s * 128 + d];
    float lv = post_f[s * 128 + 64 + d];
    sl_f[tid] = eps_noise[(size_t)b * 512 + tid] * __expf(0.5f * lv) + mu;
  }
  if (tid < 8) kl_f[tid] = 0.f;
  __syncthreads();

  // ---- iterations ----
  #pragma unroll 1
  for (int it = 0; it < 3; it++) {
    // I1: snapshot, zero, q = slots @ Wq.T + bq -> qbf (bf16 A-operand)
    {
      sp_f[tid]  = sl_f[tid];
      upd_f[tid] = 0.f;
      int s = tid >> 6, d = tid & 63;
      const float* xr = sl_f + s * 64;
      const float* wr = Wq + d * 64;
      float a = bq[d];
      #pragma unroll
      for (int ec = 0; ec < 16; ec++) {
        float4 xe = ((const float4*)xr)[ec];
        float4 w  = ((const float4*)wr)[ec];
        a = fmaf(xe.x, w.x, a); a = fmaf(xe.y, w.y, a);
        a = fmaf(xe.z, w.z, a); a = fmaf(xe.w, w.w, a);
      }
      qbf[s * 72 + d] = f2bf(a);
      qbf[(s + 8) * 72 + d] = 0;   // zero A rows 8..15
    }
    if (tid < 8) Ssum[tid] = 0.f;
    __syncthreads();

    // I2: pass A — MFMA QK^T (16 px per step), in-fragment softmax over slots
    {
      union { uint4 q; s16x8 v; } a0, a1;
      const u16* qr = qbf + col * 72 + kg * 8;
      a0.q = *(const uint4*)(qr);
      a1.q = *(const uint4*)(qr + 32);
      float s_loc[4] = {0.f, 0.f, 0.f, 0.f};

      const u16* kp0 = Kb + (size_t)(wv * 512 + col) * 64 + kg * 8;
      union { uint4 q; s16x8 v; } b0, b1, nb0, nb1;
      b0.q = *(const uint4*)(kp0);
      b1.q = *(const uint4*)(kp0 + 32);
      #pragma unroll 1
      for (int t = 0; t < 32; t++) {
        // prefetch next pixel-tile's K frags
        const u16* kpn = Kb + (size_t)(wv * 512 + (((t + 1) & 31) << 4) + col) * 64 + kg * 8;
        nb0.q = *(const uint4*)(kpn);
        nb1.q = *(const uint4*)(kpn + 32);
        f32x4 acc = {0.f, 0.f, 0.f, 0.f};
        acc = __builtin_amdgcn_mfma_f32_16x16x32_bf16(a0.v, b0.v, acc, 0, 0, 0);
        acc = __builtin_amdgcn_mfma_f32_16x16x32_bf16(a1.v, b1.v, acc, 0, 0, 0);
        // softmax over slots for pixel (wv*512 + t*16 + col)
        float d0 = acc[0] * SCALE_, d1 = acc[1] * SCALE_;
        float d2 = acc[2] * SCALE_, d3 = acc[3] * SCALE_;
        float m4 = fmaxf(fmaxf(d0, d1), fmaxf(d2, d3));
        float m8 = fmaxf(m4, __shfl_xor(m4, 16, 64));
        float e0 = __expf(d0 - m8), e1 = __expf(d1 - m8);
        float e2 = __expf(d2 - m8), e3 = __expf(d3 - m8);
        float s4 = e0 + e1 + e2 + e3;
        float s8 = s4 + __shfl_xor(s4, 16, 64);
        float rinv = 1.0f / s8;
        float v0 = fmaf(e0, rinv, EPS_), v1 = fmaf(e1, rinv, EPS_);
        float v2 = fmaf(e2, rinv, EPS_), v3 = fmaf(e3, rinv, EPS_);
        if (kg < 2) {
          const int px = wv * 512 + t * 16 + col;
          attn_u[(kg * 4 + 0) * AP_ + px] = f2bf(v0);
          attn_u[(kg * 4 + 1) * AP_ + px] = f2bf(v1);
          attn_u[(kg * 4 + 2) * AP_ + px] = f2bf(v2);
          attn_u[(kg * 4 + 3) * AP_ + px] = f2bf(v3);
          s_loc[0] += v0; s_loc[1] += v1; s_loc[2] += v2; s_loc[3] += v3;
        }
        b0 = nb0; b1 = nb1;
      }
      #pragma unroll
      for (int r = 0; r < 4; r++) {
        #pragma unroll
        for (int o = 1; o < 16; o <<= 1) s_loc[r] += __shfl_xor(s_loc[r], o, 64);
      }
      if (kg < 2 && col == 0) {
        #pragma unroll
        for (int r = 0; r < 4; r++) atomicAdd(&Ssum[kg * 4 + r], s_loc[r]);
      }
    }
    __syncthreads();

    // I3: pass B — lane owns (px-group of 8, 8-dim chunk); 4-deep V pipeline.
    {
      const int px_off = lane >> 3;        // 0..7
      const int dc = (lane & 7) * 8;       // dim chunk base
      float u[8][8];
      #pragma unroll
      for (int i = 0; i < 8; i++)
        #pragma unroll
        for (int dd = 0; dd < 8; dd++) u[i][dd] = 0.f;
      const int jbase = wv * 512;
      #pragma unroll 1
      for (int sb = 0; sb < 64; sb += 4) {
        uint4 v4[4];
        #pragma unroll
        for (int t = 0; t < 4; t++)
          v4[t] = *(const uint4*)(Vb + (size_t)(jbase + (sb + t) * 8 + px_off) * 64 + dc);
        #pragma unroll
        for (int t = 0; t < 4; t++) {
          const int j = jbase + (sb + t) * 8 + px_off;
          float vv[8];
          bf2x2(v4[t].x, vv[0], vv[1]); bf2x2(v4[t].y, vv[2], vv[3]);
          bf2x2(v4[t].z, vv[4], vv[5]); bf2x2(v4[t].w, vv[6], vv[7]);
          #pragma unroll
          for (int i = 0; i < 8; i++) {
            float a = bf2f(attn_u[i * AP_ + j]);
            #pragma unroll
            for (int dd = 0; dd < 8; dd++) u[i][dd] = fmaf(a, vv[dd], u[i][dd]);
          }
        }
      }
      #pragma unroll
      for (int i = 0; i < 8; i++)
        #pragma unroll
        for (int dd = 0; dd < 8; dd++)
          atomicAdd(upd_f + i * 64 + dc + dd, u[i][dd]);
    }
    __syncthreads();

    // I4+I5: GRU (1/S folded) + LN of GRU output -> ln_f
    {
      int s = tid >> 6, d = tid & 63;
      const float* ur  = upd_f + s * 64;
      const float* hr  = sp_f + s * 64;
      const float* wi0 = gWih + d * 64;
      const float* wi1 = gWih + (64 + d) * 64;
      const float* wi2 = gWih + (128 + d) * 64;
      const float* wh0 = gWhh + d * 64;
      const float* wh1 = gWhh + (64 + d) * 64;
      const float* wh2 = gWhh + (128 + d) * 64;
      float air=0.f, aiz=0.f, ain=0.f, ahr=0.f, ahz=0.f, ahn=0.f;
      #pragma unroll
      for (int ec = 0; ec < 16; ec++) {
        float4 xe = ((const float4*)ur)[ec];
        float4 he = ((const float4*)hr)[ec];
        float4 w;
        w = ((const float4*)wi0)[ec];
        air = fmaf(xe.x,w.x,air); air = fmaf(xe.y,w.y,air);
        air = fmaf(xe.z,w.z,air); air = fmaf(xe.w,w.w,air);
        w = ((const float4*)wi1)[ec];
        aiz = fmaf(xe.x,w.x,aiz); aiz = fmaf(xe.y,w.y,aiz);
        aiz = fmaf(xe.z,w.z,aiz); aiz = fmaf(xe.w,w.w,aiz);
        w = ((const float4*)wi2)[ec];
        ain = fmaf(xe.x,w.x,ain); ain = fmaf(xe.y,w.y,ain);
        ain = fmaf(xe.z,w.z,ain); ain = fmaf(xe.w,w.w,ain);
        w = ((const float4*)wh0)[ec];
        ahr = fmaf(he.x,w.x,ahr); ahr = fmaf(he.y,w.y,ahr);
        ahr = fmaf(he.z,w.z,ahr); ahr = fmaf(he.w,w.w,ahr);
        w = ((const float4*)wh1)[ec];
        ahz = fmaf(he.x,w.x,ahz); ahz = fmaf(he.y,w.y,ahz);
        ahz = fmaf(he.z,w.z,ahz); ahz = fmaf(he.w,w.w,ahz);
        w = ((const float4*)wh2)[ec];
        ahn = fmaf(he.x,w.x,ahn); ahn = fmaf(he.y,w.y,ahn);
        ahn = fmaf(he.z,w.z,ahn); ahn = fmaf(he.w,w.w,ahn);
      }
      float sinv = 1.0f / Ssum[s];
      float rr = 1.0f / (1.0f + __expf(-(air * sinv + gbih[d]      + ahr + gbhh[d])));
      float zz = 1.0f / (1.0f + __expf(-(aiz * sinv + gbih[64 + d] + ahz + gbhh[64 + d])));
      float nn = tanhf(ain * sinv + gbih[128 + d] + rr * (ahn + gbhh[128 + d]));
      float hnew = (1.0f - zz) * nn + zz * sp_f[tid];
      sl_f[tid] = hnew;
      float mm = wredsum(hnew) * (1.0f / 64.0f);
      float cc = hnew - mm;
      float va = wredsum(cc * cc) * (1.0f / 64.0f);
      ln_f[tid] = cc * rsqrtf(va + 1e-5f) * npf_g[d] + npf_b[d];
    }
    __syncthreads();

    // I6a: mlp hidden = relu(ln @ mW1.T + mb1)
    #pragma unroll
    for (int kk = 0; kk < 2; kk++) {
      int idx = tid + kk * 512;
      int s = idx >> 7, h = idx & 127;
      const float* xr = ln_f + s * 64;
      const float* wr = mW1 + h * 64;
      float a = mb1[h];
      #pragma unroll
      for (int ec = 0; ec < 16; ec++) {
        float4 xe = ((const float4*)xr)[ec];
        float4 w  = ((const float4*)wr)[ec];
        a = fmaf(xe.x, w.x, a); a = fmaf(xe.y, w.y, a);
        a = fmaf(xe.z, w.z, a); a = fmaf(xe.w, w.w, a);
      }
      hid_f[idx] = fmaxf(a, 0.f);
    }
    __syncthreads();
    // I6b: slots += hid @ mW2.T + mb2
    {
      int s = tid >> 6, d = tid & 63;
      const float* hh = hid_f + s * 128;
      const float* wr = mW2 + d * 128;
      float a = mb2[d];
      #pragma unroll
      for (int ec = 0; ec < 32; ec++) {
        float4 xe = ((const float4*)hh)[ec];
        float4 w  = ((const float4*)wr)[ec];
        a = fmaf(xe.x, w.x, a); a = fmaf(xe.y, w.y, a);
        a = fmaf(xe.z, w.z, a); a = fmaf(xe.w, w.w, a);
      }
      sl_f[tid] = sl_f[tid] + a;
    }
    __syncthreads();
    // I7a: post hidden
    #pragma unroll
    for (int kk = 0; kk < 2; kk++) {
      int idx = tid + kk * 512;
      int s = idx >> 7, h = idx & 127;
      const float* xr = sl_f + s * 64;
      const float* wr = sr_W1 + h * 64;
      float a = sr_b1[h];
      #pragma unroll
      for (int ec = 0; ec < 16; ec++) {
        float4 xe = ((const float4*)xr)[ec];
        float4 w  = ((const float4*)wr)[ec];
        a = fmaf(xe.x, w.x, a); a = fmaf(xe.y, w.y, a);
        a = fmaf(xe.z, w.z, a); a = fmaf(xe.w, w.w, a);
      }
      hid_f[idx] = fmaxf(a, 0.f);
    }
    __syncthreads();
    // I7b: post
    #pragma unroll
    for (int kk = 0; kk < 2; kk++) {
      int idx = tid + kk * 512;
      int s = idx >> 7, o = idx & 127;
      const float* hh = hid_f + s * 128;
      const float* wr = sr_W2 + o * 128;
      float a = sr_b2[o];
      #pragma unroll
      for (int ec = 0; ec < 32; ec++) {
        float4 xe = ((const float4*)hh)[ec];
        float4 w  = ((const float4*)wr)[ec];
        a = fmaf(xe.x, w.x, a); a = fmaf(xe.y, w.y, a);
        a = fmaf(xe.z, w.z, a); a = fmaf(xe.w, w.w, a);
      }
      post_f[idx] = a;
    }
    __syncthreads();
    // I8: KL accumulate
    {
      int s = tid >> 6, d = tid & 63;
      float m_po = post_f[s * 128 + d],  lv_po = post_f[s * 128 + 64 + d];
      float m_pr = prior_f[s * 128 + d], lv_pr = prior_f[s * 128 + 64 + d];
      float dm = m_po - m_pr;
      float term = lv_pr - lv_po + (__expf(lv_po) + dm * dm) * __expf(-lv_pr) - 1.0f;
      float tsum = wredsum(term);
      if ((tid & 63) == 0) kl_f[s] += 0.5f * tsum;
    }
    __syncthreads();
  }

  out[(size_t)b * 512 + tid] = sl_f[tid];
  if (tid < 8) out[OUT_SLOTS_ + b * 8 + tid] = kl_f[tid];
}

extern "C" void kernel_launch(void* const* d_in, const int* in_sizes, int n_in,
                              void* d_out, int out_size, void* d_ws, size_t ws_size,
                              hipStream_t stream) {
  (void)in_sizes; (void)n_in; (void)out_size; (void)ws_size;
  const float* inputs      = (const float*)d_in[0];
  const float* slots0      = (const float*)d_in[1];
  const float* prior_slots = (const float*)d_in[2];
  const float* eps_noise   = (const float*)d_in[3];
  const float* ni_g  = (const float*)d_in[4];
  const float* ni_b  = (const float*)d_in[5];
  const float* npf_g = (const float*)d_in[6];
  const float* npf_b = (const float*)d_in[7];
  const float* Wq = (const float*)d_in[8];   const float* bq = (const float*)d_in[9];
  const float* Wk = (const float*)d_in[10];  const float* bk = (const float*)d_in[11];
  const float* Wv = (const float*)d_in[12];  const float* bv = (const float*)d_in[13];
  const float* sr_W1 = (const float*)d_in[14]; const float* sr_b1 = (const float*)d_in[15];
  const float* sr_W2 = (const float*)d_in[16]; const float* sr_b2 = (const float*)d_in[17];
  const float* pr_W1 = (const float*)d_in[18]; const float* pr_b1 = (const float*)d_in[19];
  const float* pr_W2 = (const float*)d_in[20]; const float* pr_b2 = (const float*)d_in[21];
  const float* gWih = (const float*)d_in[22]; const float* gWhh = (const float*)d_in[23];
  const float* gbih = (const float*)d_in[24]; const float* gbhh = (const float*)d_in[25];
  const float* mW1 = (const float*)d_in[26]; const float* mb1 = (const float*)d_in[27];
  const float* mW2 = (const float*)d_in[28]; const float* mb2 = (const float*)d_in[29];

  u16* K = (u16*)d_ws;
  u16* V = K + (size_t)B_ * N_ * D_;

  k_lnkv<<<dim3(4096), dim3(256), 0, stream>>>(inputs, ni_g, ni_b, Wk, bk, Wv, bv, K, V);

  const int SMEM = 88512;
  hipFuncSetAttribute((const void*)k_slot, hipFuncAttributeMaxDynamicSharedMemorySize, SMEM);
  k_slot<<<dim3(256), dim3(512), SMEM, stream>>>(
      K, V, slots0, prior_slots, eps_noise, npf_g, npf_b, Wq, bq,
      sr_W1, sr_b1, sr_W2, sr_b2, pr_W1, pr_b1, pr_W2, pr_b2,
      gWih, gWhh, gbih, gbhh, mW1, mb1, mW2, mb2, (float*)d_out);
}